// Round 1
// baseline (2075.606 us; speedup 1.0000x reference)
//
#include <hip/hip_runtime.h>
#include <hip/hip_bf16.h>
#include <stdint.h>

// ---------- types / helpers ----------
typedef short short8 __attribute__((ext_vector_type(8)));   // 8 x bf16 (4 VGPRs) MFMA frag
typedef float f32x4  __attribute__((ext_vector_type(4)));   // MFMA C/D frag

__device__ __forceinline__ uint16_t f2bf(float f) {
    union { float f; uint32_t u; } v; v.f = f;
    return (uint16_t)((v.u + 0x7FFFu + ((v.u >> 16) & 1u)) >> 16);  // RNE
}
__device__ __forceinline__ float bf2f(uint16_t h) {
    union { uint32_t u; float f; } v; v.u = ((uint32_t)h) << 16;
    return v.f;
}

#define NSAMP_TOT 32768
// h1 padded layout: [s][12][17][16] bf16 (zero halo), 204 positions * 16ch
#define H1_PER_S  3264
// h2 layout: [s][p*32+c] bf16, 150*32 = 4800
#define H2_PER_S  4800

// ---------- K0a: repack fc1_w -> W1pT [256][4800] bf16, k' = p*32+c ----------
__global__ void repack_w1(const float* __restrict__ f1w, uint16_t* __restrict__ w1pt) {
    int n = threadIdx.x;            // 0..255
    int rest = blockIdx.x;          // 0..4799 = c*150+p enumerated as (c,p)
    int p = rest % 150, c = rest / 150;
    float v = f1w[(size_t)(c * 150 + p) * 256 + n];        // coalesced read over n
    w1pt[(size_t)n * 4800 + p * 32 + c] = f2bf(v);         // scattered 2B write (small)
}

// ---------- K0b: repack conv2_w -> W2rT [32][160] bf16, k = (dy*3+dx)*16+ci, pad 144..159 = 0
__global__ void repack_w2(const float* __restrict__ c2w, uint16_t* __restrict__ w2rt) {
    for (int t = threadIdx.x; t < 32 * 160; t += 256) {
        int n = t / 160, k = t % 160;
        float v = 0.f;
        if (k < 144) {
            int tap = k >> 4, ci = k & 15, dy = tap / 3, dx = tap % 3;
            v = c2w[((n * 16 + ci) * 3 + dy) * 3 + dx];
        }
        w2rt[t] = f2bf(v);
    }
}

// ---------- K1: grid build + conv1 + relu -> h1 (bf16, zero halo) ----------
// block 256, 8 samples/block. Rock channel deduped via 150-bit bitmap (set semantics).
__global__ void k1_grid_conv1(const float* __restrict__ x, const float* __restrict__ w1,
                              const float* __restrict__ b1, uint16_t* __restrict__ h1, int s0) {
    __shared__ float  sw[288];
    __shared__ float  sb[16];
    __shared__ float  sx[8 * 42];
    __shared__ uint64_t sbit[8 * 3];
    __shared__ int    srock[8];   // rocket y, or -1
    int tid = threadIdx.x;
    for (int i = tid; i < 288; i += 256) sw[i] = w1[i];
    if (tid < 16) sb[tid] = b1[tid];
    int sbase = s0 + blockIdx.x * 8;
    for (int i = tid; i < 8 * 42; i += 256) sx[i] = x[(size_t)(sbase + i / 42) * 42 + (i % 42)];
    __syncthreads();
    if (tid < 8) {
        const float* xs = &sx[tid * 42];
        uint64_t m0 = 0, m1 = 0, m2 = 0;
        #pragma unroll
        for (int r = 0; r < 20; r++) {
            int kx = (int)xs[1 + 2 * r];
            int ky = (int)xs[2 + 2 * r];
            if (kx >= 0 && kx < 15 && ky >= 0 && ky < 10) {
                int cell = ky * 15 + kx;
                if (cell < 64)        m0 |= 1ull << cell;
                else if (cell < 128)  m1 |= 1ull << (cell - 64);
                else                  m2 |= 1ull << (cell - 128);
            }
        }
        sbit[tid * 3 + 0] = m0; sbit[tid * 3 + 1] = m1; sbit[tid * 3 + 2] = m2;
        int ry = (int)xs[0];
        srock[tid] = (ry >= 0 && ry < 10) ? ry : -1;
    }
    __syncthreads();
    for (int t = tid; t < 8 * 204; t += 256) {
        int sl = t / 204, p = t % 204;
        int yp = p / 17, xp = p % 17;
        __align__(16) uint16_t outv[16];
        if (yp >= 1 && yp <= 10 && xp >= 1 && xp <= 15) {
            int y = yp - 1, xx = xp - 1;
            float acc[16];
            #pragma unroll
            for (int c = 0; c < 16; c++) acc[c] = sb[c];
            // rocket channel (0): single point (ry, col=1)
            int ry = srock[sl];
            if (ry >= 0 && ry >= y - 1 && ry <= y + 1 && xx <= 2) {
                int dy = ry - y + 1, dx = 2 - xx;   // dx = (1 - xx) + 1
                #pragma unroll
                for (int c = 0; c < 16; c++) acc[c] += sw[c * 18 + dy * 3 + dx];
            }
            // rock channel (1): 3x3 neighborhood vs bitmap
            uint64_t m0 = sbit[sl * 3], m1 = sbit[sl * 3 + 1], m2 = sbit[sl * 3 + 2];
            #pragma unroll
            for (int dy = 0; dy < 3; dy++) {
                int py = y + dy - 1;
                if (py < 0 || py >= 10) continue;
                #pragma unroll
                for (int dx = 0; dx < 3; dx++) {
                    int px = xx + dx - 1;
                    if (px < 0 || px >= 15) continue;
                    int cell = py * 15 + px;
                    uint64_t bit = (cell < 64) ? (m0 >> cell)
                                 : (cell < 128) ? (m1 >> (cell - 64)) : (m2 >> (cell - 128));
                    if (bit & 1) {
                        #pragma unroll
                        for (int c = 0; c < 16; c++) acc[c] += sw[c * 18 + 9 + dy * 3 + dx];
                    }
                }
            }
            #pragma unroll
            for (int c = 0; c < 16; c++) { float v = acc[c]; outv[c] = f2bf(v > 0.f ? v : 0.f); }
        } else {
            #pragma unroll
            for (int c = 0; c < 16; c++) outv[c] = 0;
        }
        uint16_t* dst = &h1[((size_t)(blockIdx.x * 8 + sl) * 204 + p) * 16];
        ((uint4*)dst)[0] = ((uint4*)outv)[0];
        ((uint4*)dst)[1] = ((uint4*)outv)[1];
    }
}

// ---------- K2: conv2 as implicit GEMM (M=chunk*150, K=144(pad160), N=32) + relu ----------
// tile M=128, 4 waves, each wave 32 rows x 32 cols = 2x2 frags x 5 K-steps.
__launch_bounds__(256, 2)
__global__ void k2_conv2(const uint16_t* __restrict__ h1, const uint16_t* __restrict__ w2rt,
                         const float* __restrict__ c2b, uint16_t* __restrict__ h2) {
    __shared__ __align__(16) uint16_t lA[128 * 160];
    __shared__ __align__(16) uint16_t lB[32 * 160];
    int tid = threadIdx.x;
    // stage B (weights, 10240 B)
    for (int i = tid; i < 32 * 160 / 8; i += 256) ((uint4*)lB)[i] = ((const uint4*)w2rt)[i];
    // stage A: im2col, 128 rows x 18 chunks of 16B
    int R0 = blockIdx.x * 128;
    uint4 regs[9];
    int rr[9], ii[9];
    #pragma unroll
    for (int i = 0; i < 9; i++) {
        int cidx = tid + i * 256;            // 0..2303
        int r = cidx / 18, idx = cidx % 18;
        rr[i] = r; ii[i] = idx;
        int R = R0 + r;
        int s = R / 150, p = R - s * 150;
        int y = p / 15, xx = p - y * 15;
        int tap = idx >> 1, half = idx & 1;
        int dy = tap / 3, dx = tap - dy * 3;
        const uint16_t* src = &h1[((size_t)s * 204 + (y + dy) * 17 + (xx + dx)) * 16 + half * 8];
        regs[i] = *(const uint4*)src;
    }
    #pragma unroll
    for (int i = 0; i < 9; i++) *(uint4*)&lA[rr[i] * 160 + ii[i] * 8] = regs[i];
    // zero K-pad 144..159
    for (int i = tid; i < 128 * 2; i += 256) {
        int r = i >> 1, h = i & 1;
        *(uint4*)&lA[r * 160 + 144 + h * 8] = make_uint4(0, 0, 0, 0);
    }
    __syncthreads();
    int w = tid >> 6, l = tid & 63, lr = l & 15, lk = l >> 4;
    f32x4 acc[2][2] = {};
    #pragma unroll
    for (int ks = 0; ks < 5; ks++) {
        short8 a[2], b[2];
        #pragma unroll
        for (int mf = 0; mf < 2; mf++)
            a[mf] = *(const short8*)&lA[(w * 32 + mf * 16 + lr) * 160 + ks * 32 + lk * 8];
        #pragma unroll
        for (int nf = 0; nf < 2; nf++)
            b[nf] = *(const short8*)&lB[(nf * 16 + lr) * 160 + ks * 32 + lk * 8];
        #pragma unroll
        for (int mf = 0; mf < 2; mf++)
            #pragma unroll
            for (int nf = 0; nf < 2; nf++)
                acc[mf][nf] = __builtin_amdgcn_mfma_f32_16x16x32_bf16(a[mf], b[nf], acc[mf][nf], 0, 0, 0);
    }
    float bias0 = c2b[lr], bias1 = c2b[16 + lr];
    #pragma unroll
    for (int mf = 0; mf < 2; mf++) {
        #pragma unroll
        for (int j = 0; j < 4; j++) {
            int r = w * 32 + mf * 16 + lk * 4 + j;      // D row = (lane>>4)*4 + reg
            int R = R0 + r;
            int s = R / 150, p = R - s * 150;
            size_t rb = (size_t)s * H2_PER_S + (size_t)p * 32;
            float v0 = acc[mf][0][j] + bias0;
            float v1 = acc[mf][1][j] + bias1;
            h2[rb + lr]      = f2bf(v0 > 0.f ? v0 : 0.f);   // D col = lane&15
            h2[rb + 16 + lr] = f2bf(v1 > 0.f ? v1 : 0.f);
        }
    }
}

// ---------- K3: fc1 GEMM (M=chunk, N=256, K=4800) + bias + speed rank-1 + relu ----------
// 128x128 tile, 4 waves (2x2 quadrants of 64x64), BK=64, reg-staged, XOR-swizzled LDS.
__launch_bounds__(256, 2)
__global__ void k3_fc1(const uint16_t* __restrict__ h2, const uint16_t* __restrict__ w1pt,
                       const float* __restrict__ f1b, const float* __restrict__ f1w,
                       const float* __restrict__ x, uint16_t* __restrict__ h3, int s0) {
    __shared__ __align__(16) uint16_t lA[128 * 64];
    __shared__ __align__(16) uint16_t lB[128 * 64];
    __shared__ float sbias[128], swl[128], sspeed[128];
    int tid = threadIdx.x;
    int bm = blockIdx.x, bn = blockIdx.y;
    if (tid < 128) {
        int col = bn * 128 + tid;
        sbias[tid] = f1b[col];
        swl[tid]   = f1w[(size_t)4800 * 256 + col];          // last row of fc1_w (speed)
        sspeed[tid] = x[(size_t)(s0 + bm * 128 + tid) * 42 + 41];
    }
    int w = tid >> 6, l = tid & 63, lr = l & 15, lk = l >> 4;
    int wm = w >> 1, wn = w & 1;
    f32x4 acc[4][4] = {};
    uint4 ra[4], rb[4];
    int cr[4], cj[4];
    #pragma unroll
    for (int i = 0; i < 4; i++) { int c = tid + i * 256; cr[i] = c >> 3; cj[i] = c & 7; }
    // prologue: load k-tile 0
    #pragma unroll
    for (int i = 0; i < 4; i++) {
        ra[i] = *(const uint4*)&h2[(size_t)(bm * 128 + cr[i]) * 4800 + cj[i] * 8];
        rb[i] = *(const uint4*)&w1pt[(size_t)(bn * 128 + cr[i]) * 4800 + cj[i] * 8];
    }
    for (int kt = 0; kt < 75; kt++) {
        __syncthreads();   // previous iter's LDS reads done
        #pragma unroll
        for (int i = 0; i < 4; i++) {
            int r = cr[i], j = cj[i];
            int sj = j ^ (r & 7);                      // XOR swizzle (G4)
            *(uint4*)&lA[r * 64 + sj * 8] = ra[i];
            *(uint4*)&lB[r * 64 + sj * 8] = rb[i];
        }
        __syncthreads();
        if (kt < 74) {                                  // issue-early prefetch (T14-lite)
            int k0 = (kt + 1) * 64;
            #pragma unroll
            for (int i = 0; i < 4; i++) {
                ra[i] = *(const uint4*)&h2[(size_t)(bm * 128 + cr[i]) * 4800 + k0 + cj[i] * 8];
                rb[i] = *(const uint4*)&w1pt[(size_t)(bn * 128 + cr[i]) * 4800 + k0 + cj[i] * 8];
            }
        }
        #pragma unroll
        for (int ks = 0; ks < 2; ks++) {
            short8 a[4], b[4];
            #pragma unroll
            for (int mf = 0; mf < 4; mf++) {
                int row = wm * 64 + mf * 16 + lr;
                int jj = (ks * 4 + lk) ^ (row & 7);
                a[mf] = *(const short8*)&lA[row * 64 + jj * 8];
            }
            #pragma unroll
            for (int nf = 0; nf < 4; nf++) {
                int row = wn * 64 + nf * 16 + lr;
                int jj = (ks * 4 + lk) ^ (row & 7);
                b[nf] = *(const short8*)&lB[row * 64 + jj * 8];
            }
            #pragma unroll
            for (int mf = 0; mf < 4; mf++)
                #pragma unroll
                for (int nf = 0; nf < 4; nf++)
                    acc[mf][nf] = __builtin_amdgcn_mfma_f32_16x16x32_bf16(a[mf], b[nf], acc[mf][nf], 0, 0, 0);
        }
    }
    #pragma unroll
    for (int mf = 0; mf < 4; mf++) {
        #pragma unroll
        for (int j = 0; j < 4; j++) {
            int r = wm * 64 + mf * 16 + lk * 4 + j;
            float sp = sspeed[r];
            #pragma unroll
            for (int nf = 0; nf < 4; nf++) {
                int col = wn * 64 + nf * 16 + lr;
                float v = acc[mf][nf][j] + sbias[col] + sp * swl[col];
                h3[(size_t)(bm * 128 + r) * 256 + bn * 128 + col] = f2bf(v > 0.f ? v : 0.f);
            }
        }
    }
}

// ---------- K4: fc2 + relu + fc3 (VALU f32), 4 samples/block, wave per sample ----------
__global__ void k4_fc23(const uint16_t* __restrict__ h3, const float* __restrict__ w2,
                        const float* __restrict__ b2, const float* __restrict__ w3,
                        const float* __restrict__ b3, float* __restrict__ out, int s0) {
    __shared__ float sh[4 * 256];
    int tid = threadIdx.x;
    int sl = tid >> 6, l = tid & 63;
    int s = blockIdx.x * 4 + sl;
    { // stage h3 row as f32
        const uint16_t* hr = &h3[(size_t)s * 256];
        ushort4 hv = *(const ushort4*)&hr[l * 4];
        float4 f; f.x = bf2f(hv.x); f.y = bf2f(hv.y); f.z = bf2f(hv.z); f.w = bf2f(hv.w);
        *(float4*)&sh[sl * 256 + l * 4] = f;
    }
    __syncthreads();
    const float* srow = &sh[sl * 256];
    float a0 = 0.f, a1 = 0.f;
    for (int k = 0; k < 256; k++) {
        float a = srow[k];
        float2 wv = *(const float2*)&w2[(size_t)k * 128 + l * 2];
        a0 += a * wv.x; a1 += a * wv.y;
    }
    a0 += b2[l * 2]; a1 += b2[l * 2 + 1];
    a0 = a0 > 0.f ? a0 : 0.f; a1 = a1 > 0.f ? a1 : 0.f;
    float p0 = a0 * w3[(l * 2) * 3 + 0] + a1 * w3[(l * 2 + 1) * 3 + 0];
    float p1 = a0 * w3[(l * 2) * 3 + 1] + a1 * w3[(l * 2 + 1) * 3 + 1];
    float p2 = a0 * w3[(l * 2) * 3 + 2] + a1 * w3[(l * 2 + 1) * 3 + 2];
    #pragma unroll
    for (int off = 32; off; off >>= 1) {
        p0 += __shfl_xor(p0, off);
        p1 += __shfl_xor(p1, off);
        p2 += __shfl_xor(p2, off);
    }
    if (l == 0) {
        float* o = &out[(size_t)(s0 + s) * 3];
        o[0] = p0 + b3[0]; o[1] = p1 + b3[1]; o[2] = p2 + b3[2];
    }
}

// ---------- launcher ----------
extern "C" void kernel_launch(void* const* d_in, const int* in_sizes, int n_in,
                              void* d_out, int out_size, void* d_ws, size_t ws_size,
                              hipStream_t stream) {
    const float* x   = (const float*)d_in[0];
    const float* c1w = (const float*)d_in[1];
    const float* c1b = (const float*)d_in[2];
    const float* c2w = (const float*)d_in[3];
    const float* c2b = (const float*)d_in[4];
    const float* f1w = (const float*)d_in[5];
    const float* f1b = (const float*)d_in[6];
    const float* f2w = (const float*)d_in[7];
    const float* f2b = (const float*)d_in[8];
    const float* f3w = (const float*)d_in[9];
    const float* f3b = (const float*)d_in[10];
    float* out = (float*)d_out;

    char* ws = (char*)d_ws;
    uint16_t* w1pt = (uint16_t*)ws;                        // 256*4800*2 = 2,457,600 B
    uint16_t* w2rt = (uint16_t*)(ws + 2457600);            // 32*160*2  = 10,240 B
    size_t base = 2457600 + 10240;                         // 2,467,840 (256-aligned)

    // per-sample ws: h1 6528 B + h2 9600 B + h3 512 B = 16640 B
    int chunk = NSAMP_TOT;
    while (chunk > 128 && base + (size_t)chunk * 16640 > ws_size) chunk >>= 1;
    uint16_t* h1 = (uint16_t*)(ws + base);
    uint16_t* h2 = (uint16_t*)(ws + base + (size_t)chunk * 6528);
    uint16_t* h3 = (uint16_t*)(ws + base + (size_t)chunk * (6528 + 9600));

    repack_w1<<<4800, 256, 0, stream>>>(f1w, w1pt);
    repack_w2<<<1, 256, 0, stream>>>(c2w, w2rt);

    for (int s0 = 0; s0 < NSAMP_TOT; s0 += chunk) {
        k1_grid_conv1<<<chunk / 8, 256, 0, stream>>>(x, c1w, c1b, h1, s0);
        k2_conv2<<<(chunk / 64) * 75, 256, 0, stream>>>(h1, w2rt, c2b, h2);
        k3_fc1<<<dim3(chunk / 128, 2), 256, 0, stream>>>(h2, w1pt, f1b, f1w, x, h3, s0);
        k4_fc23<<<chunk / 4, 256, 0, stream>>>(h3, f2w, f2b, f3w, f3b, out, s0);
    }
}

// Round 2
// 1275.730 us; speedup vs baseline: 1.6270x; 1.6270x over previous
//
#include <hip/hip_runtime.h>
#include <hip/hip_bf16.h>
#include <stdint.h>

// ---------- types / helpers ----------
typedef short short8 __attribute__((ext_vector_type(8)));   // 8 x bf16 (4 VGPRs) MFMA frag
typedef float f32x4  __attribute__((ext_vector_type(4)));   // MFMA C/D frag

__device__ __forceinline__ uint16_t f2bf(float f) {
    union { float f; uint32_t u; } v; v.f = f;
    return (uint16_t)((v.u + 0x7FFFu + ((v.u >> 16) & 1u)) >> 16);  // RNE
}
__device__ __forceinline__ float bf2f(uint16_t h) {
    union { uint32_t u; float f; } v; v.u = ((uint32_t)h) << 16;
    return v.f;
}

#define NSAMP_TOT 32768
#define H2_PER_S  4800   // h2 layout: [s][p*32+c] bf16, 150*32

// ---------- K0a: repack fc1_w -> W1pT [256][4800] bf16, k' = p*32+c ----------
// LDS transpose: coalesced reads, full-line (64B) writes per thread.
__global__ void repack_w1(const float* __restrict__ f1w, uint16_t* __restrict__ w1pt) {
    __shared__ float tr[32][257];
    int tid = threadIdx.x, p = blockIdx.x;            // p = 0..149
    for (int i = tid; i < 32 * 256; i += 256) {
        int c = i >> 8, n = i & 255;
        tr[c][n] = f1w[(size_t)(c * 150 + p) * 256 + n];   // coalesced over n
    }
    __syncthreads();
    int n = tid;
    uint4* dst = (uint4*)&w1pt[(size_t)n * 4800 + p * 32];  // 64B line, aligned
    #pragma unroll
    for (int q = 0; q < 4; q++) {
        uint4 v;
        v.x = (uint32_t)f2bf(tr[q*8+0][n]) | ((uint32_t)f2bf(tr[q*8+1][n]) << 16);
        v.y = (uint32_t)f2bf(tr[q*8+2][n]) | ((uint32_t)f2bf(tr[q*8+3][n]) << 16);
        v.z = (uint32_t)f2bf(tr[q*8+4][n]) | ((uint32_t)f2bf(tr[q*8+5][n]) << 16);
        v.w = (uint32_t)f2bf(tr[q*8+6][n]) | ((uint32_t)f2bf(tr[q*8+7][n]) << 16);
        dst[q] = v;
    }
}

// ---------- K0b: repack conv2_w -> W2rT [32][160] bf16, k = (dy*3+dx)*16+ci, pad 144..159 = 0
__global__ void repack_w2(const float* __restrict__ c2w, uint16_t* __restrict__ w2rt) {
    for (int t = threadIdx.x; t < 32 * 160; t += 256) {
        int n = t / 160, k = t % 160;
        float v = 0.f;
        if (k < 144) {
            int tap = k >> 4, ci = k & 15, dy = tap / 3, dx = tap % 3;
            v = c2w[((n * 16 + ci) * 3 + dy) * 3 + dx];
        }
        w2rt[t] = f2bf(v);
    }
}

// ---------- K12: grid build + conv1 (in LDS) + conv2 MFMA + relu -> h2 ----------
// 8 samples/block, 256 threads (4 waves), ~56 KB LDS -> 2 blocks/CU.
// conv2 as implicit GEMM M=8*150=1200, K=144(pad160), N=32; A-frags read straight
// from the h1 LDS tile (im2col addressing), B-frags (w2rt) held in 40 VGPRs.
__launch_bounds__(256, 2)
__global__ void k12_fused(const float* __restrict__ x, const float* __restrict__ w1,
                          const float* __restrict__ b1, const uint16_t* __restrict__ w2rt,
                          const float* __restrict__ c2b, uint16_t* __restrict__ h2, int s0) {
    __shared__ float  sw[288];
    __shared__ float  sb[16];
    __shared__ float  sx[8 * 42];
    __shared__ uint64_t sbit[8 * 3];
    __shared__ int    srock[8];
    __shared__ __align__(16) uint16_t h1s[8 * 204 * 16];   // 52,224 B, zero halo
    int tid = threadIdx.x;
    int w = tid >> 6, l = tid & 63, lr = l & 15, lk = l >> 4;

    // B-frags from global (L2-hot), issued early so latency hides under conv1.
    short8 bf[5][2];
    #pragma unroll
    for (int ks = 0; ks < 5; ks++)
        #pragma unroll
        for (int nf = 0; nf < 2; nf++)
            bf[ks][nf] = *(const short8*)&w2rt[(nf * 16 + lr) * 160 + ks * 32 + lk * 8];
    float cb0 = c2b[lr], cb1 = c2b[16 + lr];

    for (int i = tid; i < 288; i += 256) sw[i] = w1[i];
    if (tid < 16) sb[tid] = b1[tid];
    int sbase = s0 + blockIdx.x * 8;
    for (int i = tid; i < 8 * 42; i += 256) sx[i] = x[(size_t)(sbase + i / 42) * 42 + (i % 42)];
    __syncthreads();
    if (tid < 8) {
        const float* xs = &sx[tid * 42];
        uint64_t m0 = 0, m1 = 0, m2 = 0;
        #pragma unroll
        for (int r = 0; r < 20; r++) {
            int kx = (int)xs[1 + 2 * r];
            int ky = (int)xs[2 + 2 * r];
            if (kx >= 0 && kx < 15 && ky >= 0 && ky < 10) {
                int cell = ky * 15 + kx;
                if (cell < 64)        m0 |= 1ull << cell;
                else if (cell < 128)  m1 |= 1ull << (cell - 64);
                else                  m2 |= 1ull << (cell - 128);
            }
        }
        sbit[tid * 3 + 0] = m0; sbit[tid * 3 + 1] = m1; sbit[tid * 3 + 2] = m2;
        int ry = (int)xs[0];
        srock[tid] = (ry >= 0 && ry < 10) ? ry : -1;
    }
    __syncthreads();
    // conv1 + relu into LDS (halo positions zeroed)
    for (int t = tid; t < 8 * 204; t += 256) {
        int sl = t / 204, p = t % 204;
        int yp = p / 17, xp = p % 17;
        __align__(16) uint16_t outv[16];
        if (yp >= 1 && yp <= 10 && xp >= 1 && xp <= 15) {
            int y = yp - 1, xx = xp - 1;
            float acc[16];
            #pragma unroll
            for (int c = 0; c < 16; c++) acc[c] = sb[c];
            int ry = srock[sl];
            if (ry >= 0 && ry >= y - 1 && ry <= y + 1 && xx <= 2) {
                int dy = ry - y + 1, dx = 2 - xx;
                #pragma unroll
                for (int c = 0; c < 16; c++) acc[c] += sw[c * 18 + dy * 3 + dx];
            }
            uint64_t m0 = sbit[sl * 3], m1 = sbit[sl * 3 + 1], m2 = sbit[sl * 3 + 2];
            #pragma unroll
            for (int dy = 0; dy < 3; dy++) {
                int py = y + dy - 1;
                if (py < 0 || py >= 10) continue;
                #pragma unroll
                for (int dx = 0; dx < 3; dx++) {
                    int px = xx + dx - 1;
                    if (px < 0 || px >= 15) continue;
                    int cell = py * 15 + px;
                    uint64_t bit = (cell < 64) ? (m0 >> cell)
                                 : (cell < 128) ? (m1 >> (cell - 64)) : (m2 >> (cell - 128));
                    if (bit & 1) {
                        #pragma unroll
                        for (int c = 0; c < 16; c++) acc[c] += sw[c * 18 + 9 + dy * 3 + dx];
                    }
                }
            }
            #pragma unroll
            for (int c = 0; c < 16; c++) { float v = acc[c]; outv[c] = f2bf(v > 0.f ? v : 0.f); }
        } else {
            #pragma unroll
            for (int c = 0; c < 16; c++) outv[c] = 0;
        }
        uint16_t* dst = &h1s[(size_t)t * 16];
        ((uint4*)dst)[0] = ((uint4*)outv)[0];
        ((uint4*)dst)[1] = ((uint4*)outv)[1];
    }
    __syncthreads();
    // conv2 MFMA: M-frags f = 0..74 (16 rows each), wave-strided
    short8 zz = {0, 0, 0, 0, 0, 0, 0, 0};
    for (int f = w; f < 75; f += 4) {
        int rA = f * 16 + lr;                 // 0..1199
        int sA = rA / 150, pA = rA - sA * 150;
        int y = pA / 15, xx = pA - y * 15;
        f32x4 acc0 = {}, acc1 = {};
        #pragma unroll
        for (int ks = 0; ks < 5; ks++) {
            int idx = ks * 4 + lk;            // 0..19 (18,19 = K-pad)
            int idc = idx < 18 ? idx : 0;
            int tap = idc >> 1, half = idc & 1;
            int dy = tap / 3, dx = tap - dy * 3;
            short8 av = *(const short8*)&h1s[((sA * 204 + (y + dy) * 17 + (xx + dx)) * 16) + half * 8];
            av = idx < 18 ? av : zz;
            acc0 = __builtin_amdgcn_mfma_f32_16x16x32_bf16(av, bf[ks][0], acc0, 0, 0, 0);
            acc1 = __builtin_amdgcn_mfma_f32_16x16x32_bf16(av, bf[ks][1], acc1, 0, 0, 0);
        }
        #pragma unroll
        for (int j = 0; j < 4; j++) {
            int r = f * 16 + lk * 4 + j;
            int s = r / 150, p = r - s * 150;
            size_t rb = (size_t)(blockIdx.x * 8 + s) * H2_PER_S + (size_t)p * 32;
            float v0 = acc0[j] + cb0;
            float v1 = acc1[j] + cb1;
            h2[rb + lr]      = f2bf(v0 > 0.f ? v0 : 0.f);
            h2[rb + 16 + lr] = f2bf(v1 > 0.f ? v1 : 0.f);
        }
    }
}

// ---------- K3: fc1 GEMM (M=chunk, N=256 full, K=4800) + bias + speed rank-1 + relu ----------
// 128x256 tile, 512 threads (8 waves as 2x4 of 64x64), BK=64, reg-prefetch, XOR-swizzled LDS.
// h2 is read exactly once (HBM floor); w1pt (2.4 MB) stays L2-resident.
__launch_bounds__(512, 2)
__global__ void k3_fc1(const uint16_t* __restrict__ h2, const uint16_t* __restrict__ w1pt,
                       const float* __restrict__ f1b, const float* __restrict__ f1w,
                       const float* __restrict__ x, uint16_t* __restrict__ h3, int s0) {
    __shared__ __align__(16) uint16_t lA[128 * 64];   // 16 KB
    __shared__ __align__(16) uint16_t lB[256 * 64];   // 32 KB
    __shared__ float sbias[256], swl[256], sspeed[128];
    int tid = threadIdx.x;
    int bm = blockIdx.x;
    if (tid < 256) {
        sbias[tid] = f1b[tid];
        swl[tid]   = f1w[(size_t)4800 * 256 + tid];
    } else if (tid < 384) {
        sspeed[tid - 256] = x[(size_t)(s0 + bm * 128 + (tid - 256)) * 42 + 41];
    }
    int w = tid >> 6, l = tid & 63, lr = l & 15, lk = l >> 4;
    int wm = w >> 2, wn = w & 3;
    f32x4 acc[4][4] = {};
    uint4 ra[2], rb[4];
    int arr[2], arj[2], brr[4], brj[4];
    #pragma unroll
    for (int i = 0; i < 2; i++) { int c = tid + i * 512; arr[i] = c >> 3; arj[i] = c & 7; }
    #pragma unroll
    for (int i = 0; i < 4; i++) { int c = tid + i * 512; brr[i] = c >> 3; brj[i] = c & 7; }
    #pragma unroll
    for (int i = 0; i < 2; i++)
        ra[i] = *(const uint4*)&h2[(size_t)(bm * 128 + arr[i]) * 4800 + arj[i] * 8];
    #pragma unroll
    for (int i = 0; i < 4; i++)
        rb[i] = *(const uint4*)&w1pt[(size_t)brr[i] * 4800 + brj[i] * 8];
    for (int kt = 0; kt < 75; kt++) {
        __syncthreads();
        #pragma unroll
        for (int i = 0; i < 2; i++)
            *(uint4*)&lA[arr[i] * 64 + (arj[i] ^ (arr[i] & 7)) * 8] = ra[i];
        #pragma unroll
        for (int i = 0; i < 4; i++)
            *(uint4*)&lB[brr[i] * 64 + (brj[i] ^ (brr[i] & 7)) * 8] = rb[i];
        __syncthreads();
        if (kt < 74) {
            int k0 = (kt + 1) * 64;
            #pragma unroll
            for (int i = 0; i < 2; i++)
                ra[i] = *(const uint4*)&h2[(size_t)(bm * 128 + arr[i]) * 4800 + k0 + arj[i] * 8];
            #pragma unroll
            for (int i = 0; i < 4; i++)
                rb[i] = *(const uint4*)&w1pt[(size_t)brr[i] * 4800 + k0 + brj[i] * 8];
        }
        #pragma unroll
        for (int ks = 0; ks < 2; ks++) {
            short8 a[4], b[4];
            #pragma unroll
            for (int mf = 0; mf < 4; mf++) {
                int row = wm * 64 + mf * 16 + lr;
                int jj = (ks * 4 + lk) ^ (row & 7);
                a[mf] = *(const short8*)&lA[row * 64 + jj * 8];
            }
            #pragma unroll
            for (int nf = 0; nf < 4; nf++) {
                int row = wn * 64 + nf * 16 + lr;
                int jj = (ks * 4 + lk) ^ (row & 7);
                b[nf] = *(const short8*)&lB[row * 64 + jj * 8];
            }
            #pragma unroll
            for (int mf = 0; mf < 4; mf++)
                #pragma unroll
                for (int nf = 0; nf < 4; nf++)
                    acc[mf][nf] = __builtin_amdgcn_mfma_f32_16x16x32_bf16(a[mf], b[nf], acc[mf][nf], 0, 0, 0);
        }
    }
    #pragma unroll
    for (int mf = 0; mf < 4; mf++) {
        #pragma unroll
        for (int j = 0; j < 4; j++) {
            int r = wm * 64 + mf * 16 + lk * 4 + j;
            float sp = sspeed[r];
            #pragma unroll
            for (int nf = 0; nf < 4; nf++) {
                int col = wn * 64 + nf * 16 + lr;
                float v = acc[mf][nf][j] + sbias[col] + sp * swl[col];
                h3[(size_t)(bm * 128 + r) * 256 + col] = f2bf(v > 0.f ? v : 0.f);
            }
        }
    }
}

// ---------- K4: fc2 + relu + fc3 (VALU f32), 4 samples/block, wave per sample ----------
__global__ void k4_fc23(const uint16_t* __restrict__ h3, const float* __restrict__ w2,
                        const float* __restrict__ b2, const float* __restrict__ w3,
                        const float* __restrict__ b3, float* __restrict__ out, int s0) {
    __shared__ float sh[4 * 256];
    int tid = threadIdx.x;
    int sl = tid >> 6, l = tid & 63;
    int s = blockIdx.x * 4 + sl;
    {
        const uint16_t* hr = &h3[(size_t)s * 256];
        ushort4 hv = *(const ushort4*)&hr[l * 4];
        float4 f; f.x = bf2f(hv.x); f.y = bf2f(hv.y); f.z = bf2f(hv.z); f.w = bf2f(hv.w);
        *(float4*)&sh[sl * 256 + l * 4] = f;
    }
    __syncthreads();
    const float* srow = &sh[sl * 256];
    float a0 = 0.f, a1 = 0.f;
    for (int k = 0; k < 256; k++) {
        float a = srow[k];
        float2 wv = *(const float2*)&w2[(size_t)k * 128 + l * 2];
        a0 += a * wv.x; a1 += a * wv.y;
    }
    a0 += b2[l * 2]; a1 += b2[l * 2 + 1];
    a0 = a0 > 0.f ? a0 : 0.f; a1 = a1 > 0.f ? a1 : 0.f;
    float p0 = a0 * w3[(l * 2) * 3 + 0] + a1 * w3[(l * 2 + 1) * 3 + 0];
    float p1 = a0 * w3[(l * 2) * 3 + 1] + a1 * w3[(l * 2 + 1) * 3 + 1];
    float p2 = a0 * w3[(l * 2) * 3 + 2] + a1 * w3[(l * 2 + 1) * 3 + 2];
    #pragma unroll
    for (int off = 32; off; off >>= 1) {
        p0 += __shfl_xor(p0, off);
        p1 += __shfl_xor(p1, off);
        p2 += __shfl_xor(p2, off);
    }
    if (l == 0) {
        float* o = &out[(size_t)(s0 + s) * 3];
        o[0] = p0 + b3[0]; o[1] = p1 + b3[1]; o[2] = p2 + b3[2];
    }
}

// ---------- launcher ----------
extern "C" void kernel_launch(void* const* d_in, const int* in_sizes, int n_in,
                              void* d_out, int out_size, void* d_ws, size_t ws_size,
                              hipStream_t stream) {
    const float* x   = (const float*)d_in[0];
    const float* c1w = (const float*)d_in[1];
    const float* c1b = (const float*)d_in[2];
    const float* c2w = (const float*)d_in[3];
    const float* c2b = (const float*)d_in[4];
    const float* f1w = (const float*)d_in[5];
    const float* f1b = (const float*)d_in[6];
    const float* f2w = (const float*)d_in[7];
    const float* f2b = (const float*)d_in[8];
    const float* f3w = (const float*)d_in[9];
    const float* f3b = (const float*)d_in[10];
    float* out = (float*)d_out;

    char* ws = (char*)d_ws;
    uint16_t* w1pt = (uint16_t*)ws;                        // 256*4800*2 = 2,457,600 B
    uint16_t* w2rt = (uint16_t*)(ws + 2457600);            // 32*160*2  = 10,240 B
    size_t base = 2457600 + 10240;

    // per-sample ws: h2 9600 B + h3 512 B = 10112 B
    int chunk = NSAMP_TOT;
    while (chunk > 128 && base + (size_t)chunk * 10112 > ws_size) chunk >>= 1;
    uint16_t* h2 = (uint16_t*)(ws + base);
    uint16_t* h3 = (uint16_t*)(ws + base + (size_t)chunk * 9600);

    repack_w1<<<150, 256, 0, stream>>>(f1w, w1pt);
    repack_w2<<<1, 256, 0, stream>>>(c2w, w2rt);

    for (int s0 = 0; s0 < NSAMP_TOT; s0 += chunk) {
        k12_fused<<<chunk / 8, 256, 0, stream>>>(x, c1w, c1b, w2rt, c2b, h2, s0);
        k3_fc1<<<chunk / 128, 512, 0, stream>>>(h2, w1pt, f1b, f1w, x, h3, s0);
        k4_fc23<<<chunk / 4, 256, 0, stream>>>(h3, f2w, f2b, f3w, f3b, out, s0);
    }
}

// Round 4
// 650.299 us; speedup vs baseline: 3.1918x; 1.9618x over previous
//
#include <hip/hip_runtime.h>
#include <hip/hip_bf16.h>
#include <stdint.h>

// ---------- types / helpers ----------
typedef short short8 __attribute__((ext_vector_type(8)));   // 8 x bf16 (4 VGPRs) MFMA frag
typedef float f32x4  __attribute__((ext_vector_type(4)));   // MFMA C/D frag

__device__ __forceinline__ uint16_t f2bf(float f) {
    union { float f; uint32_t u; } v; v.f = f;
    return (uint16_t)((v.u + 0x7FFFu + ((v.u >> 16) & 1u)) >> 16);  // RNE
}
__device__ __forceinline__ float bf2f(uint16_t h) {
    union { uint32_t u; float f; } v; v.u = ((uint32_t)h) << 16;
    return v.f;
}
// async global->LDS, 16B per lane. LDS dest must be wave-uniform base + lane*16.
__device__ __forceinline__ void gl_lds16(const void* g, void* l) {
    __builtin_amdgcn_global_load_lds(
        (const __attribute__((address_space(1))) unsigned int*)g,
        (__attribute__((address_space(3))) unsigned int*)l, 16, 0, 0);
}

#define NSAMP_TOT 32768
#define H2_PER_S  4800   // h2 layout: [s][p*32+c] bf16, 150*32

// ---------- K0a: repack fc1_w -> W1pT [256][4800] bf16, k' = p*32+c ----------
__global__ void repack_w1(const float* __restrict__ f1w, uint16_t* __restrict__ w1pt) {
    __shared__ float tr[32][257];
    int tid = threadIdx.x, p = blockIdx.x;            // p = 0..149
    for (int i = tid; i < 32 * 256; i += 256) {
        int c = i >> 8, n = i & 255;
        tr[c][n] = f1w[(size_t)(c * 150 + p) * 256 + n];   // coalesced over n
    }
    __syncthreads();
    int n = tid;
    uint4* dst = (uint4*)&w1pt[(size_t)n * 4800 + p * 32];  // 64B line, aligned
    #pragma unroll
    for (int q = 0; q < 4; q++) {
        uint4 v;
        v.x = (uint32_t)f2bf(tr[q*8+0][n]) | ((uint32_t)f2bf(tr[q*8+1][n]) << 16);
        v.y = (uint32_t)f2bf(tr[q*8+2][n]) | ((uint32_t)f2bf(tr[q*8+3][n]) << 16);
        v.z = (uint32_t)f2bf(tr[q*8+4][n]) | ((uint32_t)f2bf(tr[q*8+5][n]) << 16);
        v.w = (uint32_t)f2bf(tr[q*8+6][n]) | ((uint32_t)f2bf(tr[q*8+7][n]) << 16);
        dst[q] = v;
    }
}

// ---------- K0b: repack conv2_w -> W2rT [32][160] bf16 ----------
__global__ void repack_w2(const float* __restrict__ c2w, uint16_t* __restrict__ w2rt) {
    for (int t = threadIdx.x; t < 32 * 160; t += 256) {
        int n = t / 160, k = t % 160;
        float v = 0.f;
        if (k < 144) {
            int tap = k >> 4, ci = k & 15, dy = tap / 3, dx = tap % 3;
            v = c2w[((n * 16 + ci) * 3 + dy) * 3 + dx];
        }
        w2rt[t] = f2bf(v);
    }
}

// ---------- K0c: repack fc2_w -> W2bT [128][256] bf16 (k-contiguous rows) ----------
__global__ void repack_w2b(const float* __restrict__ f2w, uint16_t* __restrict__ w2bt) {
    __shared__ float tr[32][129];
    int tid = threadIdx.x, b = blockIdx.x;            // b = 0..7 (k-range b*32..)
    for (int i = tid; i < 32 * 128; i += 256) {
        int kk = i >> 7, n = i & 127;
        tr[kk][n] = f2w[(size_t)(b * 32 + kk) * 128 + n];
    }
    __syncthreads();
    int n = tid >> 1, half = tid & 1;
    __align__(16) uint16_t tmp[16];
    #pragma unroll
    for (int q = 0; q < 16; q++) tmp[q] = f2bf(tr[half * 16 + q][n]);
    *(uint4*)&w2bt[(size_t)n * 256 + b * 32 + half * 16]     = *(uint4*)&tmp[0];
    *(uint4*)&w2bt[(size_t)n * 256 + b * 32 + half * 16 + 8] = *(uint4*)&tmp[8];
}

// ---------- K12: grid build + conv1 (in LDS) + conv2 MFMA + relu -> h2 ----------
__launch_bounds__(256, 2)
__global__ void k12_fused(const float* __restrict__ x, const float* __restrict__ w1,
                          const float* __restrict__ b1, const uint16_t* __restrict__ w2rt,
                          const float* __restrict__ c2b, uint16_t* __restrict__ h2, int s0) {
    __shared__ float  sw[288];
    __shared__ float  sb[16];
    __shared__ float  sx[8 * 42];
    __shared__ uint64_t sbit[8 * 3];
    __shared__ int    srock[8];
    __shared__ __align__(16) uint16_t h1s[8 * 204 * 16];   // 52,224 B, zero halo
    int tid = threadIdx.x;
    int w = tid >> 6, l = tid & 63, lr = l & 15, lk = l >> 4;

    short8 bf[5][2];
    #pragma unroll
    for (int ks = 0; ks < 5; ks++)
        #pragma unroll
        for (int nf = 0; nf < 2; nf++)
            bf[ks][nf] = *(const short8*)&w2rt[(nf * 16 + lr) * 160 + ks * 32 + lk * 8];
    float cb0 = c2b[lr], cb1 = c2b[16 + lr];

    for (int i = tid; i < 288; i += 256) sw[i] = w1[i];
    if (tid < 16) sb[tid] = b1[tid];
    int sbase = s0 + blockIdx.x * 8;
    for (int i = tid; i < 8 * 42; i += 256) sx[i] = x[(size_t)(sbase + i / 42) * 42 + (i % 42)];
    __syncthreads();
    if (tid < 8) {
        const float* xs = &sx[tid * 42];
        uint64_t m0 = 0, m1 = 0, m2 = 0;
        #pragma unroll
        for (int r = 0; r < 20; r++) {
            int kx = (int)xs[1 + 2 * r];
            int ky = (int)xs[2 + 2 * r];
            if (kx >= 0 && kx < 15 && ky >= 0 && ky < 10) {
                int cell = ky * 15 + kx;
                if (cell < 64)        m0 |= 1ull << cell;
                else if (cell < 128)  m1 |= 1ull << (cell - 64);
                else                  m2 |= 1ull << (cell - 128);
            }
        }
        sbit[tid * 3 + 0] = m0; sbit[tid * 3 + 1] = m1; sbit[tid * 3 + 2] = m2;
        int ry = (int)xs[0];
        srock[tid] = (ry >= 0 && ry < 10) ? ry : -1;
    }
    __syncthreads();
    for (int t = tid; t < 8 * 204; t += 256) {
        int sl = t / 204, p = t % 204;
        int yp = p / 17, xp = p % 17;
        __align__(16) uint16_t outv[16];
        if (yp >= 1 && yp <= 10 && xp >= 1 && xp <= 15) {
            int y = yp - 1, xx = xp - 1;
            float acc[16];
            #pragma unroll
            for (int c = 0; c < 16; c++) acc[c] = sb[c];
            int ry = srock[sl];
            if (ry >= 0 && ry >= y - 1 && ry <= y + 1 && xx <= 2) {
                int dy = ry - y + 1, dx = 2 - xx;
                #pragma unroll
                for (int c = 0; c < 16; c++) acc[c] += sw[c * 18 + dy * 3 + dx];
            }
            uint64_t m0 = sbit[sl * 3], m1 = sbit[sl * 3 + 1], m2 = sbit[sl * 3 + 2];
            #pragma unroll
            for (int dy = 0; dy < 3; dy++) {
                int py = y + dy - 1;
                if (py < 0 || py >= 10) continue;
                #pragma unroll
                for (int dx = 0; dx < 3; dx++) {
                    int px = xx + dx - 1;
                    if (px < 0 || px >= 15) continue;
                    int cell = py * 15 + px;
                    uint64_t bit = (cell < 64) ? (m0 >> cell)
                                 : (cell < 128) ? (m1 >> (cell - 64)) : (m2 >> (cell - 128));
                    if (bit & 1) {
                        #pragma unroll
                        for (int c = 0; c < 16; c++) acc[c] += sw[c * 18 + 9 + dy * 3 + dx];
                    }
                }
            }
            #pragma unroll
            for (int c = 0; c < 16; c++) { float v = acc[c]; outv[c] = f2bf(v > 0.f ? v : 0.f); }
        } else {
            #pragma unroll
            for (int c = 0; c < 16; c++) outv[c] = 0;
        }
        uint16_t* dst = &h1s[(size_t)t * 16];
        ((uint4*)dst)[0] = ((uint4*)outv)[0];
        ((uint4*)dst)[1] = ((uint4*)outv)[1];
    }
    __syncthreads();
    short8 zz = {0, 0, 0, 0, 0, 0, 0, 0};
    for (int f = w; f < 75; f += 4) {
        int rA = f * 16 + lr;
        int sA = rA / 150, pA = rA - sA * 150;
        int y = pA / 15, xx = pA - y * 15;
        f32x4 acc0 = {}, acc1 = {};
        #pragma unroll
        for (int ks = 0; ks < 5; ks++) {
            int idx = ks * 4 + lk;
            int idc = idx < 18 ? idx : 0;
            int tap = idc >> 1, half = idc & 1;
            int dy = tap / 3, dx = tap - dy * 3;
            short8 av = *(const short8*)&h1s[((sA * 204 + (y + dy) * 17 + (xx + dx)) * 16) + half * 8];
            av = idx < 18 ? av : zz;
            acc0 = __builtin_amdgcn_mfma_f32_16x16x32_bf16(av, bf[ks][0], acc0, 0, 0, 0);
            acc1 = __builtin_amdgcn_mfma_f32_16x16x32_bf16(av, bf[ks][1], acc1, 0, 0, 0);
        }
        #pragma unroll
        for (int j = 0; j < 4; j++) {
            int r = f * 16 + lk * 4 + j;
            int s = r / 150, p = r - s * 150;
            size_t rb = (size_t)(blockIdx.x * 8 + s) * H2_PER_S + (size_t)p * 32;
            float v0 = acc0[j] + cb0;
            float v1 = acc1[j] + cb1;
            h2[rb + lr]      = f2bf(v0 > 0.f ? v0 : 0.f);
            h2[rb + 16 + lr] = f2bf(v1 > 0.f ? v1 : 0.f);
        }
    }
}

// ---------- K3: fc1 GEMM, m97 structure: 128x128 tile, 4 waves, BK=64, global_load_lds ----------
__launch_bounds__(256)
__global__ void k3_fc1(const uint16_t* __restrict__ h2, const uint16_t* __restrict__ w1pt,
                       const float* __restrict__ f1b, const float* __restrict__ f1w,
                       const float* __restrict__ x, uint16_t* __restrict__ h3, int s0) {
    __shared__ __align__(16) uint16_t lA[128 * 64];   // 16 KB, linear [row][64]
    __shared__ __align__(16) uint16_t lB[128 * 64];   // 16 KB
    __shared__ float sbias[128], swl[128], sspeed[128];
    int tid = threadIdx.x;
    int bm = blockIdx.x, bn = blockIdx.y;
    if (tid < 128) {
        int col = bn * 128 + tid;
        sbias[tid] = f1b[col];
        swl[tid]   = f1w[(size_t)4800 * 256 + col];
        sspeed[tid] = x[(size_t)(s0 + bm * 128 + tid) * 42 + 41];
    }
    // staging: 4 chunks each for A,B; LDS byte off = i*4096 + tid*16 (wave-uniform + lane*16)
    int trow = tid >> 3;           // 0..31
    int tcol = (tid & 7) * 8;      // elem col within 64
    const uint16_t* ga[4]; const uint16_t* gb[4];
    uint16_t* la_[4]; uint16_t* lb_[4];
    #pragma unroll
    for (int i = 0; i < 4; i++) {
        int row = i * 32 + trow;
        ga[i] = &h2[(size_t)(bm * 128 + row) * 4800 + tcol];
        gb[i] = &w1pt[(size_t)(bn * 128 + row) * 4800 + tcol];
        la_[i] = &lA[row * 64 + tcol];
        lb_[i] = &lB[row * 64 + tcol];
    }
    int w = tid >> 6, l = tid & 63, lr = l & 15, lk = l >> 4;
    int wm = w >> 1, wn = w & 1;
    f32x4 acc[4][4] = {};
    for (int kt = 0; kt < 75; kt++) {
        #pragma unroll
        for (int i = 0; i < 4; i++) {
            gl_lds16(ga[i], la_[i]);
            gl_lds16(gb[i], lb_[i]);
            ga[i] += 64; gb[i] += 64;
        }
        __syncthreads();    // vmcnt(0) drain + barrier
        #pragma unroll
        for (int ks = 0; ks < 2; ks++) {
            short8 a[4], b[4];
            #pragma unroll
            for (int mf = 0; mf < 4; mf++)
                a[mf] = *(const short8*)&lA[(wm * 64 + mf * 16 + lr) * 64 + ks * 32 + lk * 8];
            #pragma unroll
            for (int nf = 0; nf < 4; nf++)
                b[nf] = *(const short8*)&lB[(wn * 64 + nf * 16 + lr) * 64 + ks * 32 + lk * 8];
            #pragma unroll
            for (int mf = 0; mf < 4; mf++)
                #pragma unroll
                for (int nf = 0; nf < 4; nf++)
                    acc[mf][nf] = __builtin_amdgcn_mfma_f32_16x16x32_bf16(a[mf], b[nf], acc[mf][nf], 0, 0, 0);
        }
        __syncthreads();
    }
    #pragma unroll
    for (int mf = 0; mf < 4; mf++) {
        #pragma unroll
        for (int j = 0; j < 4; j++) {
            int r = wm * 64 + mf * 16 + lk * 4 + j;
            float sp = sspeed[r];
            #pragma unroll
            for (int nf = 0; nf < 4; nf++) {
                int col = wn * 64 + nf * 16 + lr;
                float v = acc[mf][nf][j] + sbias[col] + sp * swl[col];
                h3[(size_t)(bm * 128 + r) * 256 + bn * 128 + col] = f2bf(v > 0.f ? v : 0.f);
            }
        }
    }
}

// ---------- K4: fc2 MFMA (128x128xK256) + relu + fc3 (VALU) ----------
__launch_bounds__(256)
__global__ void k4_fc23(const uint16_t* __restrict__ h3, const uint16_t* __restrict__ w2bt,
                        const float* __restrict__ b2, const float* __restrict__ w3,
                        const float* __restrict__ b3, float* __restrict__ out, int s0) {
    __shared__ __align__(16) uint16_t lH[128 * 64];
    __shared__ __align__(16) uint16_t lW[128 * 64];
    __shared__ uint16_t lF[128][132];   // padded: fc3 reads ~4-way conflict only
    __shared__ float sw3[384];
    __shared__ float sb2[128];
    int tid = threadIdx.x, bm = blockIdx.x;
    for (int i = tid; i < 384; i += 256) sw3[i] = w3[i];
    if (tid < 128) sb2[tid] = b2[tid];
    int trow = tid >> 3, tcol = (tid & 7) * 8;
    const uint16_t* ga[4]; const uint16_t* gb[4];
    uint16_t* la_[4]; uint16_t* lb_[4];
    #pragma unroll
    for (int i = 0; i < 4; i++) {
        int row = i * 32 + trow;
        ga[i] = &h3[(size_t)(bm * 128 + row) * 256 + tcol];
        gb[i] = &w2bt[(size_t)row * 256 + tcol];
        la_[i] = &lH[row * 64 + tcol];
        lb_[i] = &lW[row * 64 + tcol];
    }
    int w = tid >> 6, l = tid & 63, lr = l & 15, lk = l >> 4;
    int wm = w >> 1, wn = w & 1;
    f32x4 acc[4][4] = {};
    for (int kt = 0; kt < 4; kt++) {
        #pragma unroll
        for (int i = 0; i < 4; i++) {
            gl_lds16(ga[i], la_[i]);
            gl_lds16(gb[i], lb_[i]);
            ga[i] += 64; gb[i] += 64;
        }
        __syncthreads();
        #pragma unroll
        for (int ks = 0; ks < 2; ks++) {
            short8 a[4], b[4];
            #pragma unroll
            for (int mf = 0; mf < 4; mf++)
                a[mf] = *(const short8*)&lH[(wm * 64 + mf * 16 + lr) * 64 + ks * 32 + lk * 8];
            #pragma unroll
            for (int nf = 0; nf < 4; nf++)
                b[nf] = *(const short8*)&lW[(wn * 64 + nf * 16 + lr) * 64 + ks * 32 + lk * 8];
            #pragma unroll
            for (int mf = 0; mf < 4; mf++)
                #pragma unroll
                for (int nf = 0; nf < 4; nf++)
                    acc[mf][nf] = __builtin_amdgcn_mfma_f32_16x16x32_bf16(a[mf], b[nf], acc[mf][nf], 0, 0, 0);
        }
        __syncthreads();
    }
    // fc2 bias + relu -> lF
    #pragma unroll
    for (int mf = 0; mf < 4; mf++) {
        #pragma unroll
        for (int j = 0; j < 4; j++) {
            int r = wm * 64 + mf * 16 + lk * 4 + j;
            #pragma unroll
            for (int nf = 0; nf < 4; nf++) {
                int col = wn * 64 + nf * 16 + lr;
                float v = acc[mf][nf][j] + sb2[col];
                lF[r][col] = f2bf(v > 0.f ? v : 0.f);
            }
        }
    }
    __syncthreads();
    // fc3: one thread per sample row
    if (tid < 128) {
        float a0 = 0.f, a1 = 0.f, a2 = 0.f;
        #pragma unroll 4
        for (int n = 0; n < 128; n++) {
            float a = bf2f(lF[tid][n]);
            a0 += a * sw3[n * 3 + 0];
            a1 += a * sw3[n * 3 + 1];
            a2 += a * sw3[n * 3 + 2];
        }
        float* o = &out[(size_t)(s0 + bm * 128 + tid) * 3];
        o[0] = a0 + b3[0]; o[1] = a1 + b3[1]; o[2] = a2 + b3[2];
    }
}

// ---------- launcher ----------
extern "C" void kernel_launch(void* const* d_in, const int* in_sizes, int n_in,
                              void* d_out, int out_size, void* d_ws, size_t ws_size,
                              hipStream_t stream) {
    const float* x   = (const float*)d_in[0];
    const float* c1w = (const float*)d_in[1];
    const float* c1b = (const float*)d_in[2];
    const float* c2w = (const float*)d_in[3];
    const float* c2b = (const float*)d_in[4];
    const float* f1w = (const float*)d_in[5];
    const float* f1b = (const float*)d_in[6];
    const float* f2w = (const float*)d_in[7];
    const float* f2b = (const float*)d_in[8];
    const float* f3w = (const float*)d_in[9];
    const float* f3b = (const float*)d_in[10];
    float* out = (float*)d_out;

    char* ws = (char*)d_ws;
    uint16_t* w1pt = (uint16_t*)ws;                        // 2,457,600 B
    uint16_t* w2rt = (uint16_t*)(ws + 2457600);            // 10,240 B
    uint16_t* w2bt = (uint16_t*)(ws + 2467840);            // 65,536 B
    size_t base = 2467840 + 65536;                         // 2,533,376

    // per-sample ws: h2 9600 B + h3 512 B = 10112 B
    int chunk = NSAMP_TOT;
    while (chunk > 128 && base + (size_t)chunk * 10112 > ws_size) chunk >>= 1;
    uint16_t* h2 = (uint16_t*)(ws + base);
    uint16_t* h3 = (uint16_t*)(ws + base + (size_t)chunk * 9600);

    repack_w1<<<150, 256, 0, stream>>>(f1w, w1pt);
    repack_w2<<<1, 256, 0, stream>>>(c2w, w2rt);
    repack_w2b<<<8, 256, 0, stream>>>(f2w, w2bt);

    for (int s0 = 0; s0 < NSAMP_TOT; s0 += chunk) {
        k12_fused<<<chunk / 8, 256, 0, stream>>>(x, c1w, c1b, w2rt, c2b, h2, s0);
        k3_fc1<<<dim3(chunk / 128, 2), 256, 0, stream>>>(h2, w1pt, f1b, f1w, x, h3, s0);
        k4_fc23<<<chunk / 128, 256, 0, stream>>>(h3, w2bt, f2b, f3w, f3b, out, s0);
    }
}

// Round 5
// 416.861 us; speedup vs baseline: 4.9791x; 1.5600x over previous
//
#include <hip/hip_runtime.h>
#include <hip/hip_bf16.h>
#include <stdint.h>

// ---------- types / helpers ----------
typedef short short8 __attribute__((ext_vector_type(8)));   // 8 x bf16 (4 VGPRs) MFMA frag
typedef float f32x4  __attribute__((ext_vector_type(4)));   // MFMA C/D frag

__device__ __forceinline__ uint16_t f2bf(float f) {
    union { float f; uint32_t u; } v; v.f = f;
    return (uint16_t)((v.u + 0x7FFFu + ((v.u >> 16) & 1u)) >> 16);  // RNE
}
__device__ __forceinline__ float bf2f(uint16_t h) {
    union { uint32_t u; float f; } v; v.u = ((uint32_t)h) << 16;
    return v.f;
}
// async global->LDS, 16B per lane. LDS dest must be wave-uniform base + lane*16.
__device__ __forceinline__ void gl_lds16(const void* g, void* l) {
    __builtin_amdgcn_global_load_lds(
        (const __attribute__((address_space(1))) unsigned int*)g,
        (__attribute__((address_space(3))) unsigned int*)l, 16, 0, 0);
}

#define NSAMP_TOT 32768
#define H2_PER_S  4800   // h2 layout: [s][p*32+c] bf16, 150*32

// ---------- K0a: repack fc1_w -> W1pT [256][4800] bf16, k' = p*32+c ----------
__global__ void repack_w1(const float* __restrict__ f1w, uint16_t* __restrict__ w1pt) {
    __shared__ float tr[32][257];
    int tid = threadIdx.x, p = blockIdx.x;            // p = 0..149
    for (int i = tid; i < 32 * 256; i += 256) {
        int c = i >> 8, n = i & 255;
        tr[c][n] = f1w[(size_t)(c * 150 + p) * 256 + n];   // coalesced over n
    }
    __syncthreads();
    int n = tid;
    uint4* dst = (uint4*)&w1pt[(size_t)n * 4800 + p * 32];  // 64B line, aligned
    #pragma unroll
    for (int q = 0; q < 4; q++) {
        uint4 v;
        v.x = (uint32_t)f2bf(tr[q*8+0][n]) | ((uint32_t)f2bf(tr[q*8+1][n]) << 16);
        v.y = (uint32_t)f2bf(tr[q*8+2][n]) | ((uint32_t)f2bf(tr[q*8+3][n]) << 16);
        v.z = (uint32_t)f2bf(tr[q*8+4][n]) | ((uint32_t)f2bf(tr[q*8+5][n]) << 16);
        v.w = (uint32_t)f2bf(tr[q*8+6][n]) | ((uint32_t)f2bf(tr[q*8+7][n]) << 16);
        dst[q] = v;
    }
}

// ---------- K0b: repack conv2_w -> W2rT [32][160] ; conv1_w -> W1rT [16][32] ----------
// w2rt: k = (dy*3+dx)*16+ci, pad 144..159 = 0
// w1rt: k = (dy*3+dx)*2+ch,  pad 18..31 = 0
__global__ void repack_w2(const float* __restrict__ c2w, uint16_t* __restrict__ w2rt,
                          const float* __restrict__ c1w, uint16_t* __restrict__ w1rt) {
    for (int t = threadIdx.x; t < 32 * 160; t += 256) {
        int n = t / 160, k = t % 160;
        float v = 0.f;
        if (k < 144) {
            int tap = k >> 4, ci = k & 15, dy = tap / 3, dx = tap % 3;
            v = c2w[((n * 16 + ci) * 3 + dy) * 3 + dx];
        }
        w2rt[t] = f2bf(v);
    }
    for (int t = threadIdx.x; t < 16 * 32; t += 256) {
        int n = t >> 5, k = t & 31;
        float v = 0.f;
        if (k < 18) {
            int tap = k >> 1, ch = k & 1;
            int dy = (tap * 11) >> 5, dx = tap - dy * 3;
            v = c1w[((n * 2 + ch) * 3 + dy) * 3 + dx];
        }
        w1rt[t] = f2bf(v);
    }
}

// ---------- K12: grid scatter + conv1 MFMA + conv2 MFMA + relu -> h2 ----------
// 8 samples/block, 512 threads (8 waves). grid + h1 live entirely in LDS.
// conv1: M=1200 (8s x 150pos), K=18(pad32) = 2ch x 9taps, N=16  (A gathered as ch-pair dwords)
// conv2: M=1200, K=144(pad160), N=32 (A = 16B im2col chunks from h1s)
__launch_bounds__(512, 2)
__global__ void k12_fused(const float* __restrict__ x, const uint16_t* __restrict__ w1rt,
                          const float* __restrict__ c1b, const uint16_t* __restrict__ w2rt,
                          const float* __restrict__ c2b, uint16_t* __restrict__ h2, int s0) {
    __shared__ float sx[8 * 42];                           // 1344 B
    __shared__ __align__(16) uint16_t grd[8 * 204 * 2];    // 6528 B  [s][pos][ch]
    __shared__ __align__(16) uint16_t h1s[8 * 204 * 16];   // 52224 B [s][pos][16ch], zero halo
    int tid = threadIdx.x;
    int w = tid >> 6, l = tid & 63, lr = l & 15, lk = l >> 4;

    // register fragments from L2 (issued early)
    short8 b1f = *(const short8*)&w1rt[lr * 32 + lk * 8];
    short8 bf[5][2];
    #pragma unroll
    for (int ks = 0; ks < 5; ks++)
        #pragma unroll
        for (int nf = 0; nf < 2; nf++)
            bf[ks][nf] = *(const short8*)&w2rt[(nf * 16 + lr) * 160 + ks * 32 + lk * 8];
    float cb1r = c1b[lr];
    float cb0 = c2b[lr], cb1 = c2b[16 + lr];

    // zero grd (408 uint4) + h1s (3264 uint4)
    uint4 z4 = make_uint4(0, 0, 0, 0);
    for (int i = tid; i < 3672; i += 512) {
        if (i < 408) ((uint4*)grd)[i] = z4;
        else         ((uint4*)h1s)[i - 408] = z4;
    }
    int sbase = s0 + blockIdx.x * 8;
    for (int i = tid; i < 8 * 42; i += 512) sx[i] = x[(size_t)(sbase + i / 42) * 42 + (i % 42)];
    __syncthreads();

    // scatter: rocks (set-to-1 semantics via idempotent writes) + rocket
    if (tid < 160) {
        int sl = tid / 20, r = tid % 20;
        int kx = (int)sx[sl * 42 + 1 + 2 * r];
        int ky = (int)sx[sl * 42 + 2 + 2 * r];
        if (kx >= 0 && kx < 15 && ky >= 0 && ky < 10)
            grd[(sl * 204 + (ky + 1) * 17 + (kx + 1)) * 2 + 1] = 0x3F80;  // 1.0 bf16
    } else if (tid < 168) {
        int sl = tid - 160;
        int ry = (int)sx[sl * 42];
        if (ry >= 0 && ry < 10)
            grd[(sl * 204 + (ry + 1) * 17 + 2) * 2 + 0] = 0x3F80;
    }
    __syncthreads();

    // conv1 MFMA: 75 M-frags over 8 waves
    for (int f = w; f < 75; f += 8) {
        int rA = f * 16 + lr;
        int sA = rA / 150, pA = rA - sA * 150;
        int y = pA / 15, xx = pA - y * 15;
        int base = sA * 204 + y * 17 + xx;      // + dy*17 + dx
        union { uint32_t d[4]; short8 s; } au;
        #pragma unroll
        for (int jj = 0; jj < 4; jj++) {
            int t = lk * 4 + jj;
            int valid = t < 9;
            int tc = valid ? t : 0;
            int dy = (tc * 11) >> 5, dx = tc - dy * 3;
            uint32_t v = *(const uint32_t*)&grd[(base + dy * 17 + dx) * 2];
            au.d[jj] = valid ? v : 0u;
        }
        f32x4 acc = {};
        acc = __builtin_amdgcn_mfma_f32_16x16x32_bf16(au.s, b1f, acc, 0, 0, 0);
        #pragma unroll
        for (int j = 0; j < 4; j++) {
            int row = f * 16 + lk * 4 + j;
            int s2 = row / 150, p2 = row - s2 * 150;
            int y2 = p2 / 15, x2 = p2 - y2 * 15;
            float v = acc[j] + cb1r;
            h1s[(s2 * 204 + (y2 + 1) * 17 + (x2 + 1)) * 16 + lr] = f2bf(v > 0.f ? v : 0.f);
        }
    }
    __syncthreads();

    // conv2 MFMA: 75 M-frags over 8 waves
    short8 zz = {0, 0, 0, 0, 0, 0, 0, 0};
    for (int f = w; f < 75; f += 8) {
        int rA = f * 16 + lr;
        int sA = rA / 150, pA = rA - sA * 150;
        int y = pA / 15, xx = pA - y * 15;
        f32x4 acc0 = {}, acc1 = {};
        #pragma unroll
        for (int ks = 0; ks < 5; ks++) {
            int idx = ks * 4 + lk;
            int idc = idx < 18 ? idx : 0;
            int tap = idc >> 1, half = idc & 1;
            int dy = (tap * 11) >> 5, dx = tap - dy * 3;
            short8 av = *(const short8*)&h1s[((sA * 204 + (y + dy) * 17 + (xx + dx)) * 16) + half * 8];
            av = idx < 18 ? av : zz;
            acc0 = __builtin_amdgcn_mfma_f32_16x16x32_bf16(av, bf[ks][0], acc0, 0, 0, 0);
            acc1 = __builtin_amdgcn_mfma_f32_16x16x32_bf16(av, bf[ks][1], acc1, 0, 0, 0);
        }
        #pragma unroll
        for (int j = 0; j < 4; j++) {
            int r = f * 16 + lk * 4 + j;
            int s = r / 150, p = r - s * 150;
            size_t rb = (size_t)(blockIdx.x * 8 + s) * H2_PER_S + (size_t)p * 32;
            float v0 = acc0[j] + cb0;
            float v1 = acc1[j] + cb1;
            h2[rb + lr]      = f2bf(v0 > 0.f ? v0 : 0.f);
            h2[rb + 16 + lr] = f2bf(v1 > 0.f ? v1 : 0.f);
        }
    }
}

// ---------- K3: fc1 GEMM, 64x256 tile (full N), 4 waves, BK=64, global_load_lds ----------
// h2 read exactly once; w1pt (2.4 MB) L2-resident; grid 512 blocks = 2/CU co-residency.
__launch_bounds__(256)
__global__ void k3_fc1(const uint16_t* __restrict__ h2, const uint16_t* __restrict__ w1pt,
                       const float* __restrict__ f1b, const float* __restrict__ f1w,
                       const float* __restrict__ x, uint16_t* __restrict__ h3, int s0) {
    __shared__ __align__(16) uint16_t lA[64 * 64];    // 8 KB, linear [row][64]
    __shared__ __align__(16) uint16_t lB[256 * 64];   // 32 KB
    __shared__ float sbias[256], swl[256], sspeed[64];
    int tid = threadIdx.x;
    int bm = blockIdx.x;
    sbias[tid] = f1b[tid];
    swl[tid]   = f1w[(size_t)4800 * 256 + tid];
    if (tid < 64) sspeed[tid] = x[(size_t)(s0 + bm * 64 + tid) * 42 + 41];
    int trow = tid >> 3;           // 0..31
    int tcol = (tid & 7) * 8;      // elem col within 64
    const uint16_t* ga[2]; const uint16_t* gb[8];
    uint16_t* la_[2]; uint16_t* lb_[8];
    #pragma unroll
    for (int i = 0; i < 2; i++) {
        int row = i * 32 + trow;
        ga[i] = &h2[(size_t)(bm * 64 + row) * 4800 + tcol];
        la_[i] = &lA[row * 64 + tcol];
    }
    #pragma unroll
    for (int i = 0; i < 8; i++) {
        int row = i * 32 + trow;
        gb[i] = &w1pt[(size_t)row * 4800 + tcol];
        lb_[i] = &lB[row * 64 + tcol];
    }
    int w = tid >> 6, l = tid & 63, lr = l & 15, lk = l >> 4;
    f32x4 acc[4][4] = {};
    for (int kt = 0; kt < 75; kt++) {
        #pragma unroll
        for (int i = 0; i < 2; i++) { gl_lds16(ga[i], la_[i]); ga[i] += 64; }
        #pragma unroll
        for (int i = 0; i < 8; i++) { gl_lds16(gb[i], lb_[i]); gb[i] += 64; }
        __syncthreads();    // vmcnt(0) drain + barrier
        #pragma unroll
        for (int ks = 0; ks < 2; ks++) {
            short8 a[4], b[4];
            #pragma unroll
            for (int mf = 0; mf < 4; mf++)
                a[mf] = *(const short8*)&lA[(mf * 16 + lr) * 64 + ks * 32 + lk * 8];
            #pragma unroll
            for (int nf = 0; nf < 4; nf++)
                b[nf] = *(const short8*)&lB[(w * 64 + nf * 16 + lr) * 64 + ks * 32 + lk * 8];
            #pragma unroll
            for (int mf = 0; mf < 4; mf++)
                #pragma unroll
                for (int nf = 0; nf < 4; nf++)
                    acc[mf][nf] = __builtin_amdgcn_mfma_f32_16x16x32_bf16(a[mf], b[nf], acc[mf][nf], 0, 0, 0);
        }
        __syncthreads();
    }
    #pragma unroll
    for (int mf = 0; mf < 4; mf++) {
        #pragma unroll
        for (int j = 0; j < 4; j++) {
            int r = mf * 16 + lk * 4 + j;
            float sp = sspeed[r];
            #pragma unroll
            for (int nf = 0; nf < 4; nf++) {
                int col = w * 64 + nf * 16 + lr;
                float v = acc[mf][nf][j] + sbias[col] + sp * swl[col];
                h3[(size_t)(bm * 64 + r) * 256 + col] = f2bf(v > 0.f ? v : 0.f);
            }
        }
    }
}

// ---------- K0c: repack fc2_w -> W2bT [128][256] bf16 (k-contiguous rows) ----------
__global__ void repack_w2b(const float* __restrict__ f2w, uint16_t* __restrict__ w2bt) {
    __shared__ float tr[32][129];
    int tid = threadIdx.x, b = blockIdx.x;            // b = 0..7 (k-range b*32..)
    for (int i = tid; i < 32 * 128; i += 256) {
        int kk = i >> 7, n = i & 127;
        tr[kk][n] = f2w[(size_t)(b * 32 + kk) * 128 + n];
    }
    __syncthreads();
    int n = tid >> 1, half = tid & 1;
    __align__(16) uint16_t tmp[16];
    #pragma unroll
    for (int q = 0; q < 16; q++) tmp[q] = f2bf(tr[half * 16 + q][n]);
    *(uint4*)&w2bt[(size_t)n * 256 + b * 32 + half * 16]     = *(uint4*)&tmp[0];
    *(uint4*)&w2bt[(size_t)n * 256 + b * 32 + half * 16 + 8] = *(uint4*)&tmp[8];
}

// ---------- K4: fc2 MFMA (128x128xK256) + relu + fc3 (VALU) ----------
__launch_bounds__(256)
__global__ void k4_fc23(const uint16_t* __restrict__ h3, const uint16_t* __restrict__ w2bt,
                        const float* __restrict__ b2, const float* __restrict__ w3,
                        const float* __restrict__ b3, float* __restrict__ out, int s0) {
    __shared__ __align__(16) uint16_t lH[128 * 64];
    __shared__ __align__(16) uint16_t lW[128 * 64];
    __shared__ uint16_t lF[128][132];   // padded: fc3 reads ~4-way conflict only
    __shared__ float sw3[384];
    __shared__ float sb2[128];
    int tid = threadIdx.x, bm = blockIdx.x;
    for (int i = tid; i < 384; i += 256) sw3[i] = w3[i];
    if (tid < 128) sb2[tid] = b2[tid];
    int trow = tid >> 3, tcol = (tid & 7) * 8;
    const uint16_t* ga[4]; const uint16_t* gb[4];
    uint16_t* la_[4]; uint16_t* lb_[4];
    #pragma unroll
    for (int i = 0; i < 4; i++) {
        int row = i * 32 + trow;
        ga[i] = &h3[(size_t)(bm * 128 + row) * 256 + tcol];
        gb[i] = &w2bt[(size_t)row * 256 + tcol];
        la_[i] = &lH[row * 64 + tcol];
        lb_[i] = &lW[row * 64 + tcol];
    }
    int w = tid >> 6, l = tid & 63, lr = l & 15, lk = l >> 4;
    int wm = w >> 1, wn = w & 1;
    f32x4 acc[4][4] = {};
    for (int kt = 0; kt < 4; kt++) {
        #pragma unroll
        for (int i = 0; i < 4; i++) {
            gl_lds16(ga[i], la_[i]);
            gl_lds16(gb[i], lb_[i]);
            ga[i] += 64; gb[i] += 64;
        }
        __syncthreads();
        #pragma unroll
        for (int ks = 0; ks < 2; ks++) {
            short8 a[4], b[4];
            #pragma unroll
            for (int mf = 0; mf < 4; mf++)
                a[mf] = *(const short8*)&lH[(wm * 64 + mf * 16 + lr) * 64 + ks * 32 + lk * 8];
            #pragma unroll
            for (int nf = 0; nf < 4; nf++)
                b[nf] = *(const short8*)&lW[(wn * 64 + nf * 16 + lr) * 64 + ks * 32 + lk * 8];
            #pragma unroll
            for (int mf = 0; mf < 4; mf++)
                #pragma unroll
                for (int nf = 0; nf < 4; nf++)
                    acc[mf][nf] = __builtin_amdgcn_mfma_f32_16x16x32_bf16(a[mf], b[nf], acc[mf][nf], 0, 0, 0);
        }
        __syncthreads();
    }
    // fc2 bias + relu -> lF
    #pragma unroll
    for (int mf = 0; mf < 4; mf++) {
        #pragma unroll
        for (int j = 0; j < 4; j++) {
            int r = wm * 64 + mf * 16 + lk * 4 + j;
            #pragma unroll
            for (int nf = 0; nf < 4; nf++) {
                int col = wn * 64 + nf * 16 + lr;
                float v = acc[mf][nf][j] + sb2[col];
                lF[r][col] = f2bf(v > 0.f ? v : 0.f);
            }
        }
    }
    __syncthreads();
    // fc3: one thread per sample row
    if (tid < 128) {
        float a0 = 0.f, a1 = 0.f, a2 = 0.f;
        #pragma unroll 4
        for (int n = 0; n < 128; n++) {
            float a = bf2f(lF[tid][n]);
            a0 += a * sw3[n * 3 + 0];
            a1 += a * sw3[n * 3 + 1];
            a2 += a * sw3[n * 3 + 2];
        }
        float* o = &out[(size_t)(s0 + bm * 128 + tid) * 3];
        o[0] = a0 + b3[0]; o[1] = a1 + b3[1]; o[2] = a2 + b3[2];
    }
}

// ---------- launcher ----------
extern "C" void kernel_launch(void* const* d_in, const int* in_sizes, int n_in,
                              void* d_out, int out_size, void* d_ws, size_t ws_size,
                              hipStream_t stream) {
    const float* x   = (const float*)d_in[0];
    const float* c1w = (const float*)d_in[1];
    const float* c1b = (const float*)d_in[2];
    const float* c2w = (const float*)d_in[3];
    const float* c2b = (const float*)d_in[4];
    const float* f1w = (const float*)d_in[5];
    const float* f1b = (const float*)d_in[6];
    const float* f2w = (const float*)d_in[7];
    const float* f2b = (const float*)d_in[8];
    const float* f3w = (const float*)d_in[9];
    const float* f3b = (const float*)d_in[10];
    float* out = (float*)d_out;

    char* ws = (char*)d_ws;
    uint16_t* w1pt = (uint16_t*)ws;                        // 2,457,600 B
    uint16_t* w2rt = (uint16_t*)(ws + 2457600);            // 10,240 B
    uint16_t* w2bt = (uint16_t*)(ws + 2467840);            // 65,536 B
    uint16_t* w1rt = (uint16_t*)(ws + 2533376);            // 1,024 B
    size_t base = 2534400;

    // per-sample ws: h2 9600 B + h3 512 B = 10112 B
    int chunk = NSAMP_TOT;
    while (chunk > 128 && base + (size_t)chunk * 10112 > ws_size) chunk >>= 1;
    uint16_t* h2 = (uint16_t*)(ws + base);
    uint16_t* h3 = (uint16_t*)(ws + base + (size_t)chunk * 9600);

    repack_w1<<<150, 256, 0, stream>>>(f1w, w1pt);
    repack_w2<<<1, 256, 0, stream>>>(c2w, w2rt, c1w, w1rt);
    repack_w2b<<<8, 256, 0, stream>>>(f2w, w2bt);

    for (int s0 = 0; s0 < NSAMP_TOT; s0 += chunk) {
        k12_fused<<<chunk / 8, 512, 0, stream>>>(x, w1rt, c1b, w2rt, c2b, h2, s0);
        k3_fc1<<<chunk / 64, 256, 0, stream>>>(h2, w1pt, f1b, f1w, x, h3, s0);
        k4_fc23<<<chunk / 128, 256, 0, stream>>>(h3, w2bt, f2b, f3w, f3b, out, s0);
    }
}

// Round 6
// 407.136 us; speedup vs baseline: 5.0981x; 1.0239x over previous
//
#include <hip/hip_runtime.h>
#include <hip/hip_bf16.h>
#include <stdint.h>

// ---------- types / helpers ----------
typedef short short8 __attribute__((ext_vector_type(8)));   // 8 x bf16 (4 VGPRs) MFMA frag
typedef float f32x4  __attribute__((ext_vector_type(4)));   // MFMA C/D frag

__device__ __forceinline__ uint16_t f2bf(float f) {
    union { float f; uint32_t u; } v; v.f = f;
    return (uint16_t)((v.u + 0x7FFFu + ((v.u >> 16) & 1u)) >> 16);  // RNE
}
__device__ __forceinline__ float bf2f(uint16_t h) {
    union { uint32_t u; float f; } v; v.u = ((uint32_t)h) << 16;
    return v.f;
}
// async global->LDS, 16B per lane. LDS dest must be wave-uniform base + lane*16.
__device__ __forceinline__ void gl_lds16(const void* g, void* l) {
    __builtin_amdgcn_global_load_lds(
        (const __attribute__((address_space(1))) unsigned int*)g,
        (__attribute__((address_space(3))) unsigned int*)l, 16, 0, 0);
}

#define NSAMP_TOT 32768
// h2 layout: [s][k'] bf16, k' = (p/16)*512 + c*16 + (p%16), K padded to 5120 (p padded to 160)
#define H2_PER_S  5120

// ---------- K0a: repack fc1_w -> W1pT [256][5120] bf16, k' = (p/16)*512 + c*16 + p%16 ----------
// pad slots (p >= 150) are ZERO so h2 pad values contribute nothing.
__global__ void repack_w1(const float* __restrict__ f1w, uint16_t* __restrict__ w1pt) {
    __shared__ float tr[32][257];
    int tid = threadIdx.x, p160 = blockIdx.x;         // 0..159
    int f_s = p160 >> 4, p_loc = p160 & 15;
    bool valid = p160 < 150;
    for (int i = tid; i < 32 * 256; i += 256) {
        int c = i >> 8, n = i & 255;
        tr[c][n] = valid ? f1w[(size_t)(c * 150 + p160) * 256 + n] : 0.f;
    }
    __syncthreads();
    int n = tid;
    size_t base = (size_t)n * H2_PER_S + f_s * 512 + p_loc;
    #pragma unroll
    for (int c = 0; c < 32; c++)
        w1pt[base + c * 16] = f2bf(tr[c][n]);
}

// ---------- K0b: repack conv2_w -> W2rT [32][160] ; conv1_w -> W1rT [16][32] ----------
__global__ void repack_w2(const float* __restrict__ c2w, uint16_t* __restrict__ w2rt,
                          const float* __restrict__ c1w, uint16_t* __restrict__ w1rt) {
    for (int t = threadIdx.x; t < 32 * 160; t += 256) {
        int n = t / 160, k = t % 160;
        float v = 0.f;
        if (k < 144) {
            int tap = k >> 4, ci = k & 15, dy = tap / 3, dx = tap % 3;
            v = c2w[((n * 16 + ci) * 3 + dy) * 3 + dx];
        }
        w2rt[t] = f2bf(v);
    }
    for (int t = threadIdx.x; t < 16 * 32; t += 256) {
        int n = t >> 5, k = t & 31;
        float v = 0.f;
        if (k < 18) {
            int tap = k >> 1, ch = k & 1;
            int dy = (tap * 11) >> 5, dx = tap - dy * 3;
            v = c1w[((n * 2 + ch) * 3 + dy) * 3 + dx];
        }
        w1rt[t] = f2bf(v);
    }
}

// ---------- K0c: repack fc2_w -> W2bT [128][256] bf16 (k-contiguous rows) ----------
__global__ void repack_w2b(const float* __restrict__ f2w, uint16_t* __restrict__ w2bt) {
    __shared__ float tr[32][129];
    int tid = threadIdx.x, b = blockIdx.x;            // b = 0..7 (k-range b*32..)
    for (int i = tid; i < 32 * 128; i += 256) {
        int kk = i >> 7, n = i & 127;
        tr[kk][n] = f2w[(size_t)(b * 32 + kk) * 128 + n];
    }
    __syncthreads();
    int n = tid >> 1, half = tid & 1;
    __align__(16) uint16_t tmp[16];
    #pragma unroll
    for (int q = 0; q < 16; q++) tmp[q] = f2bf(tr[half * 16 + q][n]);
    *(uint4*)&w2bt[(size_t)n * 256 + b * 32 + half * 16]     = *(uint4*)&tmp[0];
    *(uint4*)&w2bt[(size_t)n * 256 + b * 32 + half * 16 + 8] = *(uint4*)&tmp[8];
}

// ---------- K12: grid scatter + conv1 MFMA + conv2 MFMA + relu -> h2 (coalesced) ----------
// 8 samples/block, 512 threads (8 waves). grid + h1 entirely in LDS.
__launch_bounds__(512, 2)
__global__ void k12_fused(const float* __restrict__ x, const uint16_t* __restrict__ w1rt,
                          const float* __restrict__ c1b, const uint16_t* __restrict__ w2rt,
                          const float* __restrict__ c2b, uint16_t* __restrict__ h2, int s0) {
    __shared__ float sx[8 * 42];                           // 1344 B
    __shared__ __align__(16) uint16_t grd[8 * 204 * 2];    // 6528 B  [s][pos][ch]
    __shared__ __align__(16) uint16_t h1s[8 * 204 * 16];   // 52224 B [s][pos][16ch], zero halo
    int tid = threadIdx.x;
    int w = tid >> 6, l = tid & 63, lr = l & 15, lk = l >> 4;

    // register fragments from L2 (issued early)
    short8 b1f = *(const short8*)&w1rt[lr * 32 + lk * 8];
    short8 bfr[5][2];
    #pragma unroll
    for (int ks = 0; ks < 5; ks++)
        #pragma unroll
        for (int nf = 0; nf < 2; nf++)
            bfr[ks][nf] = *(const short8*)&w2rt[(nf * 16 + lr) * 160 + ks * 32 + lk * 8];
    float cb1r = c1b[lr];
    float cb0 = c2b[lr], cb1 = c2b[16 + lr];

    // zero grd (408 uint4) + h1s (3264 uint4)
    uint4 z4 = make_uint4(0, 0, 0, 0);
    for (int i = tid; i < 3672; i += 512) {
        if (i < 408) ((uint4*)grd)[i] = z4;
        else         ((uint4*)h1s)[i - 408] = z4;
    }
    int sbase = s0 + blockIdx.x * 8;
    for (int i = tid; i < 8 * 42; i += 512) sx[i] = x[(size_t)(sbase + i / 42) * 42 + (i % 42)];
    __syncthreads();

    // scatter: rocks (set-to-1 semantics, idempotent writes) + rocket
    if (tid < 160) {
        int sl = tid / 20, r = tid % 20;
        int kx = (int)sx[sl * 42 + 1 + 2 * r];
        int ky = (int)sx[sl * 42 + 2 + 2 * r];
        if (kx >= 0 && kx < 15 && ky >= 0 && ky < 10)
            grd[(sl * 204 + (ky + 1) * 17 + (kx + 1)) * 2 + 1] = 0x3F80;  // 1.0 bf16
    } else if (tid < 168) {
        int sl = tid - 160;
        int ry = (int)sx[sl * 42];
        if (ry >= 0 && ry < 10)
            grd[(sl * 204 + (ry + 1) * 17 + 2) * 2 + 0] = 0x3F80;
    }
    __syncthreads();

    // conv1 MFMA: 75 M-frags over 8 waves (no barrier inside; uneven trips ok)
    for (int f = w; f < 75; f += 8) {
        int rA = f * 16 + lr;
        int sA = rA / 150, pA = rA - sA * 150;
        int y = pA / 15, xx = pA - y * 15;
        int base = sA * 204 + y * 17 + xx;
        union { uint32_t d[4]; short8 s; } au;
        #pragma unroll
        for (int jj = 0; jj < 4; jj++) {
            int t = lk * 4 + jj;
            int valid = t < 9;
            int tc = valid ? t : 0;
            int dy = (tc * 11) >> 5, dx = tc - dy * 3;
            uint32_t v = *(const uint32_t*)&grd[(base + dy * 17 + dx) * 2];
            au.d[jj] = valid ? v : 0u;
        }
        f32x4 acc = {};
        acc = __builtin_amdgcn_mfma_f32_16x16x32_bf16(au.s, b1f, acc, 0, 0, 0);
        #pragma unroll
        for (int j = 0; j < 4; j++) {
            int row = f * 16 + lk * 4 + j;
            int s2 = row / 150, p2 = row - s2 * 150;
            int y2 = p2 / 15, x2 = p2 - y2 * 15;
            float v = acc[j] + cb1r;
            h1s[(s2 * 204 + (y2 + 1) * 17 + (x2 + 1)) * 16 + lr] = f2bf(v > 0.f ? v : 0.f);
        }
    }
    __syncthreads();

    // conv2 MFMA: 80 M-frags (8 samples x 10 f_s, p padded to 160) -> coalesced ushort4 stores
    short8 zz = {0, 0, 0, 0, 0, 0, 0, 0};
    for (int f = w; f < 80; f += 8) {
        int s_local = f / 10, f_s = f - s_local * 10;
        int p160 = f_s * 16 + lr;
        int pA = p160 < 150 ? p160 : 0;       // pad rows: clamp (values harmless, w1pt=0 there)
        int y = pA / 15, xx = pA - y * 15;
        f32x4 acc0 = {}, acc1 = {};
        #pragma unroll
        for (int ks = 0; ks < 5; ks++) {
            int idx = ks * 4 + lk;
            int idc = idx < 18 ? idx : 0;
            int tap = idc >> 1, half = idc & 1;
            int dy = (tap * 11) >> 5, dx = tap - dy * 3;
            short8 av = *(const short8*)&h1s[((s_local * 204 + (y + dy) * 17 + (xx + dx)) * 16) + half * 8];
            av = idx < 18 ? av : zz;
            acc0 = __builtin_amdgcn_mfma_f32_16x16x32_bf16(av, bfr[ks][0], acc0, 0, 0, 0);
            acc1 = __builtin_amdgcn_mfma_f32_16x16x32_bf16(av, bfr[ks][1], acc1, 0, 0, 0);
        }
        // store: k' = f_s*512 + c*16 + p_loc ; pack j=0..3 (consecutive p) into ushort4
        size_t base = (size_t)(blockIdx.x * 8 + s_local) * H2_PER_S + f_s * 512 + lr * 16 + lk * 4;
        ushort4 v0, v1;
        { float a = acc0[0] + cb0; v0.x = f2bf(a > 0.f ? a : 0.f); }
        { float a = acc0[1] + cb0; v0.y = f2bf(a > 0.f ? a : 0.f); }
        { float a = acc0[2] + cb0; v0.z = f2bf(a > 0.f ? a : 0.f); }
        { float a = acc0[3] + cb0; v0.w = f2bf(a > 0.f ? a : 0.f); }
        { float a = acc1[0] + cb1; v1.x = f2bf(a > 0.f ? a : 0.f); }
        { float a = acc1[1] + cb1; v1.y = f2bf(a > 0.f ? a : 0.f); }
        { float a = acc1[2] + cb1; v1.z = f2bf(a > 0.f ? a : 0.f); }
        { float a = acc1[3] + cb1; v1.w = f2bf(a > 0.f ? a : 0.f); }
        *(ushort4*)&h2[base]       = v0;
        *(ushort4*)&h2[base + 256] = v1;
    }
}

// ---------- K3: fc1 GEMM (64x256 tile, K=5120) + bias + speed + relu + fc2 MFMA + fc3 -> out ----------
__launch_bounds__(256)
__global__ void k3_fused(const uint16_t* __restrict__ h2, const uint16_t* __restrict__ w1pt,
                         const float* __restrict__ f1b, const float* __restrict__ f1w,
                         const float* __restrict__ x, const uint16_t* __restrict__ w2bt,
                         const float* __restrict__ f2b, const float* __restrict__ f3w,
                         const float* __restrict__ f3b, float* __restrict__ out, int s0) {
    __shared__ __align__(16) uint16_t lA[64 * 64];    // 8 KB
    __shared__ __align__(16) uint16_t lB[256 * 64];   // 32 KB
    __shared__ __align__(16) uint16_t lH[64 * 256];   // 32 KB (swizzled h3 tile)
    __shared__ float sbias[256], swl[256], sspeed[64], sb2[128], sw3[384];
    __shared__ float pf[2][64][3];
    int tid = threadIdx.x;
    int bm = blockIdx.x;
    sbias[tid] = f1b[tid];
    swl[tid]   = f1w[(size_t)4800 * 256 + tid];
    if (tid < 64)  sspeed[tid] = x[(size_t)(s0 + bm * 64 + tid) * 42 + 41];
    if (tid < 128) sb2[tid] = f2b[tid];
    for (int i = tid; i < 384; i += 256) sw3[i] = f3w[i];
    int trow = tid >> 3;           // 0..31
    int tcol = (tid & 7) * 8;      // elem col within 64
    const uint16_t* ga[2]; const uint16_t* gb[8];
    uint16_t* la_[2]; uint16_t* lb_[8];
    #pragma unroll
    for (int i = 0; i < 2; i++) {
        int row = i * 32 + trow;
        ga[i] = &h2[(size_t)(bm * 64 + row) * H2_PER_S + tcol];
        la_[i] = &lA[row * 64 + tcol];
    }
    #pragma unroll
    for (int i = 0; i < 8; i++) {
        int row = i * 32 + trow;
        gb[i] = &w1pt[(size_t)row * H2_PER_S + tcol];
        lb_[i] = &lB[row * 64 + tcol];
    }
    int w = tid >> 6, l = tid & 63, lr = l & 15, lk = l >> 4;
    f32x4 acc[4][4] = {};
    for (int kt = 0; kt < 80; kt++) {
        #pragma unroll
        for (int i = 0; i < 2; i++) { gl_lds16(ga[i], la_[i]); ga[i] += 64; }
        #pragma unroll
        for (int i = 0; i < 8; i++) { gl_lds16(gb[i], lb_[i]); gb[i] += 64; }
        __syncthreads();    // vmcnt(0) drain + barrier
        #pragma unroll
        for (int ks = 0; ks < 2; ks++) {
            short8 a[4], b[4];
            #pragma unroll
            for (int mf = 0; mf < 4; mf++)
                a[mf] = *(const short8*)&lA[(mf * 16 + lr) * 64 + ks * 32 + lk * 8];
            #pragma unroll
            for (int nf = 0; nf < 4; nf++)
                b[nf] = *(const short8*)&lB[(w * 64 + nf * 16 + lr) * 64 + ks * 32 + lk * 8];
            #pragma unroll
            for (int mf = 0; mf < 4; mf++)
                #pragma unroll
                for (int nf = 0; nf < 4; nf++)
                    acc[mf][nf] = __builtin_amdgcn_mfma_f32_16x16x32_bf16(a[mf], b[nf], acc[mf][nf], 0, 0, 0);
        }
        __syncthreads();
    }
    // fc1 epilogue: bias + speed rank-1 + relu -> lH (16B-chunk XOR swizzle on columns)
    #pragma unroll
    for (int mf = 0; mf < 4; mf++) {
        #pragma unroll
        for (int j = 0; j < 4; j++) {
            int r = mf * 16 + lk * 4 + j;
            float sp = sspeed[r];
            #pragma unroll
            for (int nf = 0; nf < 4; nf++) {
                int col = w * 64 + nf * 16 + lr;
                float v = acc[mf][nf][j] + sbias[col] + sp * swl[col];
                int cc = col >> 3, cl = col & 7;
                lH[r * 256 + ((cc ^ (r & 7)) << 3) + cl] = f2bf(v > 0.f ? v : 0.f);
            }
        }
    }
    __syncthreads();
    // fc2: M=64, N=128, K=256. 4 waves: mh = w>>1 (32 rows), nh = w&1 (64 cols).
    int mh = w >> 1, nh = w & 1;
    f32x4 acc2[2][4] = {};
    #pragma unroll
    for (int ks2 = 0; ks2 < 8; ks2++) {
        short8 a2[2], bv[4];
        #pragma unroll
        for (int mf2 = 0; mf2 < 2; mf2++) {
            int row = mh * 32 + mf2 * 16 + lr;
            int chunk = (ks2 * 4 + lk) ^ (row & 7);
            a2[mf2] = *(const short8*)&lH[row * 256 + chunk * 8];
        }
        #pragma unroll
        for (int nf2 = 0; nf2 < 4; nf2++)
            bv[nf2] = *(const short8*)&w2bt[(size_t)(nh * 64 + nf2 * 16 + lr) * 256 + ks2 * 32 + lk * 8];
        #pragma unroll
        for (int mf2 = 0; mf2 < 2; mf2++)
            #pragma unroll
            for (int nf2 = 0; nf2 < 4; nf2++)
                acc2[mf2][nf2] = __builtin_amdgcn_mfma_f32_16x16x32_bf16(a2[mf2], bv[nf2], acc2[mf2][nf2], 0, 0, 0);
    }
    // fc3: relu(fc2+b2) dot w3 (3 outputs); per-lane partials then 16-lane reduce
    float p3[2][4][3];
    #pragma unroll
    for (int mf2 = 0; mf2 < 2; mf2++)
        #pragma unroll
        for (int j = 0; j < 4; j++)
            #pragma unroll
            for (int o = 0; o < 3; o++) p3[mf2][j][o] = 0.f;
    #pragma unroll
    for (int mf2 = 0; mf2 < 2; mf2++) {
        #pragma unroll
        for (int nf2 = 0; nf2 < 4; nf2++) {
            int col = nh * 64 + nf2 * 16 + lr;
            float w0 = sw3[col * 3 + 0], w1v = sw3[col * 3 + 1], w2v = sw3[col * 3 + 2];
            #pragma unroll
            for (int j = 0; j < 4; j++) {
                float v = acc2[mf2][nf2][j] + sb2[col];
                v = v > 0.f ? v : 0.f;
                p3[mf2][j][0] += v * w0;
                p3[mf2][j][1] += v * w1v;
                p3[mf2][j][2] += v * w2v;
            }
        }
    }
    #pragma unroll
    for (int off = 1; off < 16; off <<= 1)
        #pragma unroll
        for (int mf2 = 0; mf2 < 2; mf2++)
            #pragma unroll
            for (int j = 0; j < 4; j++)
                #pragma unroll
                for (int o = 0; o < 3; o++)
                    p3[mf2][j][o] += __shfl_xor(p3[mf2][j][o], off);
    if (lr == 0) {
        #pragma unroll
        for (int mf2 = 0; mf2 < 2; mf2++)
            #pragma unroll
            for (int j = 0; j < 4; j++) {
                int r = mh * 32 + mf2 * 16 + lk * 4 + j;
                #pragma unroll
                for (int o = 0; o < 3; o++) pf[nh][r][o] = p3[mf2][j][o];
            }
    }
    __syncthreads();
    if (tid < 192) {
        int r = tid / 3, o = tid - r * 3;
        out[(size_t)(s0 + bm * 64 + r) * 3 + o] = pf[0][r][o] + pf[1][r][o] + f3b[o];
    }
}

// ---------- launcher ----------
extern "C" void kernel_launch(void* const* d_in, const int* in_sizes, int n_in,
                              void* d_out, int out_size, void* d_ws, size_t ws_size,
                              hipStream_t stream) {
    const float* x   = (const float*)d_in[0];
    const float* c1w = (const float*)d_in[1];
    const float* c1b = (const float*)d_in[2];
    const float* c2w = (const float*)d_in[3];
    const float* c2b = (const float*)d_in[4];
    const float* f1w = (const float*)d_in[5];
    const float* f1b = (const float*)d_in[6];
    const float* f2w = (const float*)d_in[7];
    const float* f2b = (const float*)d_in[8];
    const float* f3w = (const float*)d_in[9];
    const float* f3b = (const float*)d_in[10];
    float* out = (float*)d_out;

    char* ws = (char*)d_ws;
    uint16_t* w1pt = (uint16_t*)ws;                        // 256*5120*2 = 2,621,440 B
    uint16_t* w2rt = (uint16_t*)(ws + 2621440);            // 10,240 B
    uint16_t* w2bt = (uint16_t*)(ws + 2631680);            // 65,536 B
    uint16_t* w1rt = (uint16_t*)(ws + 2697216);            // 1,024 B
    size_t base = 2698240;

    // per-sample ws: h2 = 5120*2 = 10,240 B
    int chunk = NSAMP_TOT;
    while (chunk > 128 && base + (size_t)chunk * 10240 > ws_size) chunk >>= 1;
    uint16_t* h2 = (uint16_t*)(ws + base);

    repack_w1<<<160, 256, 0, stream>>>(f1w, w1pt);
    repack_w2<<<1, 256, 0, stream>>>(c2w, w2rt, c1w, w1rt);
    repack_w2b<<<8, 256, 0, stream>>>(f2w, w2bt);

    for (int s0 = 0; s0 < NSAMP_TOT; s0 += chunk) {
        k12_fused<<<chunk / 8, 512, 0, stream>>>(x, w1rt, c1b, w2rt, c2b, h2, s0);
        k3_fused<<<chunk / 64, 256, 0, stream>>>(h2, w1pt, f1b, f1w, x, w2bt, f2b, f3w, f3b, out, s0);
    }
}